// Round 2
// baseline (10293.929 us; speedup 1.0000x reference)
//
#include <hip/hip_runtime.h>
#include <hip/hip_bf16.h>

#define N_B 128

// ---- output offsets (f32 elements), reference return order ----
#define OUT_RECON 0          // [128,1,64,64]  = 524288
#define OUT_CODES 524288     // [128,4,4]      = 2048
#define OUT_LC    526336     // commitment, codebook, vq  (3 scalars)
#define OUT_NL    526339     // [128,4,4,4096] = 8388608
#define OUT_NCT   8914947    // [128,4,4]      = 2048

// ---- workspace layout (float elements) ----
#define WS_A     0                    // 33554432 f32 : h1 / DOTS / d3-out
#define WS_B     33554432             // 8388608      : h2 / d2-out
#define WS_C     41943040             // 2097152      : h3 / d1-out
#define WS_Z4    44040192             // 524288       : z grid, later zq grid
#define WS_ZF    44564480             // 524288       : zf rows [2048][256]
#define WS_ZSQ   45088768             // 2048
#define WS_CBSQ  45090816             // 4096
#define WS_EMB   45094912             // 278528       : [128][2176]
#define WS_H1    45373440             // 32768
#define WS_H2    45406208             // 32768
#define WS_ACC   45438976             // 16           : loss accumulator
#define WS_CODES 45438992             // 2048 ints
#define WS_WT2   45441040             // 3 x 1048576 f32 transposed enc weights
#define WS_WT3   (WS_WT2+1048576)
#define WS_WT4   (WS_WT3+1048576)
// total = 48586768 floats = 194.3 MB

// ---------- weight prep ----------
// encoder conv weight [oc][ic][4][4] f32 -> [ic][oc][16] f32
__global__ __launch_bounds__(256) void k_wtrans(const float* __restrict__ w, float* __restrict__ o){
  int i = blockIdx.x*256 + threadIdx.x;      // output index
  int k = i & 15, oc = (i>>4) & 255, ic = i>>12;
  o[i] = w[(((size_t)oc<<8) + ic)*16 + k];
}
// codebook squared norms
__global__ __launch_bounds__(256) void k_cbsq(const float* __restrict__ cb, float* __restrict__ cbsq){
  int c = blockIdx.x*256 + threadIdx.x;
  const float4* r4 = (const float4*)(cb + (size_t)c*256);
  float s = 0.f;
  for(int k=0;k<64;k++){
    float4 v = r4[k];
    s += v.x*v.x + v.y*v.y + v.z*v.z + v.w*v.w;
  }
  cbsq[c] = s;
}

// ---------- encoder conv1: [B,1,64,64] -> [B,256,32,32], relu ----------
__global__ __launch_bounds__(256) void k_conv1(const float* __restrict__ x, const float* __restrict__ w,
                                               const float* __restrict__ bias, float* __restrict__ out){
  int ow = threadIdx.x & 31, oh = (blockIdx.x<<3) + (threadIdx.x>>5);
  int oc = blockIdx.y, b = blockIdx.z;
  float wv[16];
  #pragma unroll
  for(int k=0;k<16;k++) wv[k] = w[oc*16+k];   // oc block-uniform -> scalar loads
  const float* xb = x + (size_t)b*4096;
  float acc = bias[oc];
  int ih0 = 2*oh-1, iw0 = 2*ow-1;
  #pragma unroll
  for(int kh=0;kh<4;kh++){
    int ih = ih0+kh;
    if((unsigned)ih >= 64u) continue;
    #pragma unroll
    for(int kw=0;kw<4;kw++){
      int iw = iw0+kw;
      if((unsigned)iw >= 64u) continue;
      acc += wv[kh*4+kw]*xb[ih*64+iw];
    }
  }
  out[(((size_t)b*256+oc)*32+oh)*32+ow] = fmaxf(acc, 0.f);
}

// ---------- generic stride-2 conv, IC=OC=256, f32 in/out ----------
// block: 64 threads, each thread handles oc = t, t+64, t+128, t+192 over a 2x2 output tile.
template<bool RELU>
__global__ __launch_bounds__(64) void k_conv_mid(const float* __restrict__ in, const float* __restrict__ wt,
                                                 const float* __restrict__ bias, float* __restrict__ out, int Hin){
  int Hout = Hin>>1, tw = Hout>>1;
  int oh0 = (blockIdx.x/tw)*2, ow0 = (blockIdx.x%tw)*2;
  int b = blockIdx.y, t = threadIdx.x;
  __shared__ __align__(16) float patch[64][6][8];
  float acc[4][4];
  #pragma unroll
  for(int q=0;q<4;q++){
    float bv = bias[t+64*q];
    #pragma unroll
    for(int s=0;s<4;s++) acc[q][s]=bv;
  }
  int r0 = 2*oh0-1, c0 = 2*ow0-1;
  const float* inb = in + (size_t)b*256*Hin*Hin;
  for(int ic0=0; ic0<256; ic0+=64){
    __syncthreads();
    for(int i=t; i<64*36; i+=64){
      int icl = i/36, rem = i - icl*36;
      int rr = rem/6, cc = rem - rr*6;
      int r = r0+rr, c = c0+cc;
      float v = 0.f;
      if((unsigned)r < (unsigned)Hin && (unsigned)c < (unsigned)Hin)
        v = inb[(size_t)(ic0+icl)*Hin*Hin + r*Hin + c];
      patch[icl][rr][cc] = v;
    }
    __syncthreads();
    for(int icl=0; icl<64; icl++){
      float p[6][6];
      #pragma unroll
      for(int rr=0;rr<6;rr++){
        float4 v0 = *(const float4*)&patch[icl][rr][0];
        float2 v1 = *(const float2*)&patch[icl][rr][4];
        p[rr][0]=v0.x; p[rr][1]=v0.y; p[rr][2]=v0.z; p[rr][3]=v0.w;
        p[rr][4]=v1.x; p[rr][5]=v1.y;
      }
      const float* wrow = wt + ((size_t)(ic0+icl)*256 + t)*16;
      #pragma unroll
      for(int q=0;q<4;q++){
        const float4* w4p = (const float4*)(wrow + q*64*16);
        float4 a0=w4p[0], a1=w4p[1], a2=w4p[2], a3=w4p[3];
        float wv[16] = {a0.x,a0.y,a0.z,a0.w, a1.x,a1.y,a1.z,a1.w,
                        a2.x,a2.y,a2.z,a2.w, a3.x,a3.y,a3.z,a3.w};
        #pragma unroll
        for(int kh=0;kh<4;kh++){
          #pragma unroll
          for(int kw=0;kw<4;kw++){
            float w = wv[kh*4+kw];
            acc[q][0] += w*p[kh  ][kw  ];
            acc[q][1] += w*p[kh  ][kw+2];
            acc[q][2] += w*p[kh+2][kw  ];
            acc[q][3] += w*p[kh+2][kw+2];
          }
        }
      }
    }
  }
  #pragma unroll
  for(int q=0;q<4;q++){
    float* ob = out + ((size_t)b*256 + (t+64*q))*(size_t)(Hout*Hout);
    #pragma unroll
    for(int s=0;s<4;s++){
      float v = acc[q][s];
      if(RELU) v = fmaxf(v, 0.f);
      ob[(oh0+(s>>1))*Hout + ow0 + (s&1)] = v;
    }
  }
}

// ---------- zf pack + squared norms ----------
__global__ __launch_bounds__(256) void k_zfpack(const float* __restrict__ z4, float* __restrict__ zf,
                                                float* __restrict__ zsq){
  int r = blockIdx.x, c = threadIdx.x;
  int b = r>>4, g = r&15, gy = g>>2, gx = g&3;
  float v = z4[(((size_t)b*256+c)*4+gy)*4+gx];
  zf[(size_t)r*256+c] = v;
  __shared__ float red[256];
  red[c] = v*v; __syncthreads();
  for(int s=128;s>0;s>>=1){ if(c<s) red[c]+=red[c+s]; __syncthreads(); }
  if(c==0) zsq[r] = red[0];
}

// ---------- generic tiled GEMM, 128x128 block tile, 8x8 thread tile ----------
// MODE 0: C f32 = A[MxK] * B[NxK]^T   (VQ dots, B = codebook)
// MODE 1: C f32 = A[MxK] * B[KxN] + bias  (dynamics head)
template<int MODE>
__global__ __launch_bounds__(256) void k_gemm(const float* __restrict__ A, const float* __restrict__ Bm,
                                              const float* __restrict__ bias, float* __restrict__ C,
                                              int M, int N, int K){
  __shared__ __align__(16) float As[16][132];
  __shared__ __align__(16) float Bs[16][132];
  int m0 = blockIdx.y*128, n0 = blockIdx.x*128;
  int t = threadIdx.x;
  int tm = (t>>4)*8, tn = (t&15)*8;
  float acc[8][8] = {};
  for(int k0=0; k0<K; k0+=16){
    __syncthreads();
    for(int i=t;i<2048;i+=256){
      int k=i&15, m=i>>4;
      As[k][m] = A[(size_t)(m0+m)*K + k0+k];
    }
    if(MODE==0){
      for(int i=t;i<2048;i+=256){
        int k=i&15, n=i>>4;
        Bs[k][n] = Bm[(size_t)(n0+n)*K + k0+k];
      }
    } else {
      for(int i=t;i<2048;i+=256){
        int n=i&127, k=i>>7;
        Bs[k][n] = Bm[(size_t)(k0+k)*N + n0+n];
      }
    }
    __syncthreads();
    #pragma unroll
    for(int k=0;k<16;k++){
      float a[8], bb[8];
      *(float4*)&a[0]  = *(const float4*)&As[k][tm];
      *(float4*)&a[4]  = *(const float4*)&As[k][tm+4];
      *(float4*)&bb[0] = *(const float4*)&Bs[k][tn];
      *(float4*)&bb[4] = *(const float4*)&Bs[k][tn+4];
      #pragma unroll
      for(int i=0;i<8;i++)
        #pragma unroll
        for(int j=0;j<8;j++) acc[i][j] += a[i]*bb[j];
    }
  }
  if(MODE==0){
    #pragma unroll
    for(int i=0;i<8;i++)
      #pragma unroll
      for(int j=0;j<8;j+=4)
        *(float4*)&C[(size_t)(m0+tm+i)*N + n0+tn+j] = *(float4*)&acc[i][j];
  } else {
    float bv[8];
    #pragma unroll
    for(int j=0;j<8;j++) bv[j] = bias[n0+tn+j];
    #pragma unroll
    for(int i=0;i<8;i++)
      #pragma unroll
      for(int j=0;j<8;j++)
        C[(size_t)(m0+tm+i)*N + n0+tn+j] = acc[i][j] + bv[j];
  }
}

// ---------- VQ argmin (matches np.argmin first-min tie-break) ----------
__global__ __launch_bounds__(256) void k_argmin(const float* __restrict__ dots, const float* __restrict__ zsq,
                                                const float* __restrict__ cbsq, int* __restrict__ codes,
                                                float* __restrict__ out_codes){
  int r = blockIdx.x, t = threadIdx.x;
  float zs = zsq[r];
  float bv = 1e30f; int bi = 0x7fffffff;
  for(int c=t; c<4096; c+=256){
    float d = zs + cbsq[c] - 2.f*dots[(size_t)r*4096+c];
    if(d < bv || (d==bv && c<bi)){ bv=d; bi=c; }
  }
  __shared__ float sv[256]; __shared__ int si[256];
  sv[t]=bv; si[t]=bi; __syncthreads();
  for(int s=128;s>0;s>>=1){
    if(t<s){
      float v2=sv[t+s]; int i2=si[t+s];
      if(v2 < sv[t] || (v2==sv[t] && i2<si[t])){ sv[t]=v2; si[t]=i2; }
    }
    __syncthreads();
  }
  if(t==0){ codes[r]=si[0]; out_codes[r]=(float)si[0]; }
}

__global__ void k_zero(float* a){ a[0]=0.f; }

// zq gather + commitment/codebook loss accumulation; writes zq into z-grid layout
__global__ __launch_bounds__(256) void k_zqloss(const float* __restrict__ zf, const float* __restrict__ cb,
                                                const int* __restrict__ codes, float* __restrict__ zq4,
                                                float* __restrict__ accum){
  int r = blockIdx.x, c = threadIdx.x;
  int code = codes[r];
  float q = cb[(size_t)code*256 + c];
  float d = zf[(size_t)r*256+c] - q;
  int b = r>>4, g = r&15;
  zq4[(((size_t)b*256+c)*4+(g>>2))*4+(g&3)] = q;
  __shared__ float red[256];
  red[c] = d*d; __syncthreads();
  for(int s=128;s>0;s>>=1){ if(c<s) red[c]+=red[c+s]; __syncthreads(); }
  if(c==0) atomicAdd(accum, red[0]);
}

__global__ void k_final(const float* __restrict__ accum, float* __restrict__ out){
  if(threadIdx.x==0){
    float L = accum[0]*(1.f/524288.f);
    out[0] = L;          // commitment
    out[1] = L;          // codebook (same forward value)
    out[2] = 1.25f*L;    // codebook + 0.25*commitment
  }
}

// ---------- deconv (ConvTranspose2d k4 s2 p1), IC=OC=256, relu ----------
// weights in native [ic][oc][4][4] layout. block: 128 threads,
// thread handles oc = t, t+128 over a 4x4 output tile.
__global__ __launch_bounds__(128) void k_deconv(const float* __restrict__ in, const float* __restrict__ w,
                                                const float* __restrict__ bias, float* __restrict__ out, int Hin){
  int Hout = Hin*2, tw = Hout>>2;
  int oy0 = (blockIdx.x/tw)*4, ox0 = (blockIdx.x%tw)*4;
  int b = blockIdx.y, t = threadIdx.x;
  __shared__ __align__(16) float patch[64][4][4];
  float acc[2][16];
  #pragma unroll
  for(int q=0;q<2;q++){
    float bv = bias[t+128*q];
    #pragma unroll
    for(int s=0;s<16;s++) acc[q][s]=bv;
  }
  int iy0 = (oy0>>1)-1, ix0 = (ox0>>1)-1;
  const float* inb = in + (size_t)b*256*Hin*Hin;
  for(int ic0=0; ic0<256; ic0+=64){
    __syncthreads();
    for(int i=t; i<64*16; i+=128){
      int cc=i&3, rr=(i>>2)&3, icl=i>>4;
      int r=iy0+rr, c=ix0+cc;
      float v=0.f;
      if((unsigned)r < (unsigned)Hin && (unsigned)c < (unsigned)Hin)
        v = inb[(size_t)(ic0+icl)*Hin*Hin + r*Hin + c];
      patch[icl][rr][cc]=v;
    }
    __syncthreads();
    for(int icl=0; icl<64; icl++){
      float4 r0=*(const float4*)&patch[icl][0][0];
      float4 r1=*(const float4*)&patch[icl][1][0];
      float4 r2=*(const float4*)&patch[icl][2][0];
      float4 r3=*(const float4*)&patch[icl][3][0];
      float p[4][4] = {{r0.x,r0.y,r0.z,r0.w},{r1.x,r1.y,r1.z,r1.w},
                       {r2.x,r2.y,r2.z,r2.w},{r3.x,r3.y,r3.z,r3.w}};
      const float* wrow = w + ((size_t)(ic0+icl)*256 + t)*16;
      #pragma unroll
      for(int q=0;q<2;q++){
        const float4* w4p = (const float4*)(wrow + q*128*16);
        float4 a0=w4p[0], a1=w4p[1], a2=w4p[2], a3=w4p[3];
        float wv[16] = {a0.x,a0.y,a0.z,a0.w, a1.x,a1.y,a1.z,a1.w,
                        a2.x,a2.y,a2.z,a2.w, a3.x,a3.y,a3.z,a3.w};
        #pragma unroll
        for(int dy=0;dy<4;dy++){
          const int khh=(dy+1)&1, prh=1+((dy+1)>>1);
          #pragma unroll
          for(int dx=0;dx<4;dx++){
            const int kwh=(dx+1)&1, pch=1+((dx+1)>>1);
            float s = wv[khh*4+kwh]        * p[prh  ][pch  ]
                    + wv[khh*4+kwh+2]      * p[prh  ][pch-1]
                    + wv[(khh+2)*4+kwh]    * p[prh-1][pch  ]
                    + wv[(khh+2)*4+kwh+2]  * p[prh-1][pch-1];
            acc[q][dy*4+dx] += s;
          }
        }
      }
    }
  }
  #pragma unroll
  for(int q=0;q<2;q++){
    float* ob = out + ((size_t)b*256 + t+128*q)*(size_t)(Hout*Hout);
    #pragma unroll
    for(int dy=0;dy<4;dy++)
      #pragma unroll
      for(int dx=0;dx<4;dx++)
        ob[(oy0+dy)*Hout + ox0+dx] = fmaxf(acc[q][dy*4+dx], 0.f);
  }
}

// ---------- final deconv (OC=1) + sigmoid -> recon ----------
__global__ __launch_bounds__(256) void k_dec4(const float* __restrict__ in, const float* __restrict__ w4,
                                              const float* __restrict__ bias, float* __restrict__ out){
  int ox = threadIdx.x & 63, oy = (blockIdx.x<<2) + (threadIdx.x>>6), b = blockIdx.y;
  int iyh=(oy+1)>>1, kh=(oy+1)&1;
  int ixh=(ox+1)>>1, kw=(ox+1)&1;
  bool y0 = iyh<32, y1 = iyh>=1;
  bool xa = ixh<32, xb = ixh>=1;
  const float* inb = in + (size_t)b*256*1024;
  float acc = bias[0];
  for(int ic=0; ic<256; ic++){
    const float* p = inb + (size_t)ic*1024;
    float w00=w4[ic*16+kh*4+kw];
    float w01=w4[ic*16+kh*4+kw+2];
    float w10=w4[ic*16+(kh+2)*4+kw];
    float w11=w4[ic*16+(kh+2)*4+kw+2];
    if(y0){ if(xa) acc += w00*p[iyh*32+ixh]; if(xb) acc += w01*p[iyh*32+ixh-1]; }
    if(y1){ if(xa) acc += w10*p[(iyh-1)*32+ixh]; if(xb) acc += w11*p[(iyh-1)*32+ixh-1]; }
  }
  float s = 1.f/(1.f+__expf(-acc));
  out[(size_t)b*4096 + oy*64 + ox] = s;
}

// ---------- dynamics ----------
__global__ __launch_bounds__(256) void k_embed(const int* __restrict__ codes, const int* __restrict__ action,
                                               const float* __restrict__ ce, const float* __restrict__ ae,
                                               float* __restrict__ emb){
  int b = blockIdx.x;
  for(int j=threadIdx.x; j<2176; j+=256){
    float v;
    if(j<2048){ int g=j>>7; v = ce[(size_t)codes[b*16+g]*128 + (j&127)]; }
    else      { v = ae[(size_t)action[b]*128 + (j-2048)]; }
    emb[(size_t)b*2176+j] = v;
  }
}

__global__ __launch_bounds__(256) void k_mlp(const float* __restrict__ in, const float* __restrict__ w,
                                             const float* __restrict__ bias, float* __restrict__ out, int K){
  int b = blockIdx.x, n = threadIdx.x;
  extern __shared__ float row[];
  for(int k=n;k<K;k+=256) row[k]=in[(size_t)b*K+k];
  __syncthreads();
  float acc = bias[n];
  for(int k=0;k<K;k++) acc += row[k]*w[(size_t)k*256+n];
  out[(size_t)b*256+n] = fmaxf(acc, 0.f);
}

extern "C" void kernel_launch(void* const* d_in, const int* in_sizes, int n_in,
                              void* d_out, int out_size, void* d_ws, size_t ws_size,
                              hipStream_t stream){
  (void)in_sizes; (void)n_in; (void)out_size; (void)ws_size;
  const float* x    = (const float*)d_in[0];
  const float* xn   = (const float*)d_in[1];
  const int*   act  = (const int*)  d_in[2];
  const float* ew1=(const float*)d_in[3];  const float* eb1=(const float*)d_in[4];
  const float* ew2=(const float*)d_in[5];  const float* eb2=(const float*)d_in[6];
  const float* ew3=(const float*)d_in[7];  const float* eb3=(const float*)d_in[8];
  const float* ew4=(const float*)d_in[9];  const float* eb4=(const float*)d_in[10];
  const float* dw1=(const float*)d_in[11]; const float* db1=(const float*)d_in[12];
  const float* dw2=(const float*)d_in[13]; const float* db2=(const float*)d_in[14];
  const float* dw3=(const float*)d_in[15]; const float* db3=(const float*)d_in[16];
  const float* dw4=(const float*)d_in[17]; const float* db4=(const float*)d_in[18];
  const float* cbk =(const float*)d_in[19];
  const float* cemb=(const float*)d_in[20];
  const float* aemb=(const float*)d_in[21];
  const float* yw1=(const float*)d_in[22]; const float* yb1=(const float*)d_in[23];
  const float* yw2=(const float*)d_in[24]; const float* yb2=(const float*)d_in[25];
  const float* yw3=(const float*)d_in[26]; const float* yb3=(const float*)d_in[27];
  float* out = (float*)d_out;

  float* W  = (float*)d_ws;
  float* A  = W+WS_A;  float* Bb = W+WS_B;  float* Cc = W+WS_C;
  float* Z4 = W+WS_Z4; float* ZF = W+WS_ZF; float* ZSQ=W+WS_ZSQ; float* CBSQ=W+WS_CBSQ;
  float* EMB=W+WS_EMB; float* H1 = W+WS_H1; float* H2 = W+WS_H2; float* ACC=W+WS_ACC;
  int*   CODES=(int*)(W+WS_CODES);
  float* WT2=W+WS_WT2; float* WT3=W+WS_WT3; float* WT4=W+WS_WT4;
  float* DOTS = A;   // aliases h1 (dead by the time dots are computed)

  // weight prep (encoder transposes only; decoder weights already [ic][oc][16])
  k_wtrans<<<4096,256,0,stream>>>(ew2, WT2);
  k_wtrans<<<4096,256,0,stream>>>(ew3, WT3);
  k_wtrans<<<4096,256,0,stream>>>(ew4, WT4);
  k_cbsq  <<<16,  256,0,stream>>>(cbk, CBSQ);

  auto encode = [&](const float* img, float* code_out){
    k_conv1<<<dim3(4,256,N_B),256,0,stream>>>(img, ew1, eb1, A);
    k_conv_mid<true ><<<dim3(64,N_B),64,0,stream>>>(A,  WT2, eb2, Bb, 32);
    k_conv_mid<true ><<<dim3(16,N_B),64,0,stream>>>(Bb, WT3, eb3, Cc, 16);
    k_conv_mid<false><<<dim3(4 ,N_B),64,0,stream>>>(Cc, WT4, eb4, Z4, 8);
    k_zfpack<<<2048,256,0,stream>>>(Z4, ZF, ZSQ);
    k_gemm<0><<<dim3(32,16),256,0,stream>>>(ZF, cbk, nullptr, DOTS, 2048, 4096, 256);
    k_argmin<<<2048,256,0,stream>>>(DOTS, ZSQ, CBSQ, CODES, code_out);
  };

  // ---- encode(x) + VQ ----
  encode(x, out+OUT_CODES);
  k_zero<<<1,1,0,stream>>>(ACC);
  k_zqloss<<<2048,256,0,stream>>>(ZF, cbk, CODES, Z4, ACC);   // Z4 becomes zq grid
  k_final<<<1,64,0,stream>>>(ACC, out+OUT_LC);

  // ---- decoder ----
  k_deconv<<<dim3(4 ,N_B),128,0,stream>>>(Z4, dw1, db1, Cc, 4);
  k_deconv<<<dim3(16,N_B),128,0,stream>>>(Cc, dw2, db2, Bb, 8);
  k_deconv<<<dim3(64,N_B),128,0,stream>>>(Bb, dw3, db3, A, 16);
  k_dec4  <<<dim3(16,N_B),256,0,stream>>>(A, dw4, db4, out+OUT_RECON);

  // ---- dynamics ----
  k_embed<<<N_B,256,0,stream>>>(CODES, act, cemb, aemb, EMB);
  k_mlp<<<N_B,256,2176*4,stream>>>(EMB, yw1, yb1, H1, 2176);
  k_mlp<<<N_B,256, 256*4,stream>>>(H1,  yw2, yb2, H2, 256);
  k_gemm<1><<<dim3(512,1),256,0,stream>>>(H2, yw3, yb3, out+OUT_NL, 128, 65536, 256);

  // ---- encode(x_next) for targets (reuses all buffers; decoder/dynamics done) ----
  encode(xn, out+OUT_NCT);
}

// Round 4
// 2131.588 us; speedup vs baseline: 4.8292x; 4.8292x over previous
//
#include <hip/hip_runtime.h>
#include <hip/hip_bf16.h>

typedef _Float16 f16;
typedef f16   f16x8 __attribute__((ext_vector_type(8)));
typedef short s16x8 __attribute__((ext_vector_type(8)));
typedef float f32x4 __attribute__((ext_vector_type(4)));
typedef unsigned short u16;

__device__ __forceinline__ f32x4 mfma_f16(f16x8 a, f16x8 b, f32x4 c){
  return __builtin_amdgcn_mfma_f32_16x16x32_f16(a,b,c,0,0,0);
}
__device__ __forceinline__ f32x4 mfma_bf16(s16x8 a, s16x8 b, f32x4 c){
  return __builtin_amdgcn_mfma_f32_16x16x32_bf16(a,b,c,0,0,0);
}
__device__ __forceinline__ u16 f2bf(float v){
  unsigned u = __float_as_uint(v);
  unsigned r = u + 0x7fffu + ((u>>16)&1u);
  return (u16)(r>>16);
}
__device__ __forceinline__ float bf2f(u16 v){ return __uint_as_float(((unsigned)v)<<16); }

#define N_B 128

// ---- output offsets (f32 elements), reference return order ----
#define OUT_RECON 0
#define OUT_CODES 524288
#define OUT_LC    526336
#define OUT_NL    526339
#define OUT_NCT   8914947

// ---- workspace layout (BYTE offsets) ----
// Region R1 (64MiB): E1H, later D3.  Region R2 (64MiB): E1L, later everything
// below (all lifetimes disjoint, verified against launch order).  Region R3
// (32MiB): E2H+E2L, later DOTS.  Persistent: packed weights, CBSQ, zero guard.
#define B_E1H  0ull
#define B_E1L  67108864ull
#define B_ZF   67108864ull              // [2048,256] f32 (2MiB)         in R2
#define B_ZQ4  69206016ull              // [2048,256] bf16 (1MiB)        in R2
#define B_ZSQ  70254592ull              // 8KiB                          in R2
#define B_ACC  70287360ull              //                               in R2
#define B_CODES 70320128ull             // 8KiB                          in R2
#define B_H1   70385664ull              // 128KiB                        in R2
#define B_H2   70516736ull              // 128KiB                        in R2
#define B_E3H  71303168ull              // 4MiB (alias D1)               in R2
#define B_E3L  75497472ull              // 4MiB (alias D2 head)          in R2
#define B_D1   71303168ull              // [128,8,8,256] bf16 4MiB       in R2
#define B_D2   75497472ull              // [128,16,16,256] bf16 16MiB    in R2
#define B_EMB  92274688ull              // [128][2176] f32 (~1.1MiB)     in R2
#define B_E2H  134217728ull             // 16MiB                         R3
#define B_E2L  150994944ull             // 16MiB                         R3
#define B_DOTS 134217728ull             // 32MiB aliases E2H+E2L         R3
#define B_WE2H 167772160ull             // persistent packed weights (2MiB each)
#define B_WE2L 169869312ull
#define B_WE3H 171966464ull
#define B_WE3L 174063616ull
#define B_WE4H 176160768ull
#define B_WE4L 178257920ull
#define B_WD1  180355072ull
#define B_WD2  182452224ull
#define B_WD3  184549376ull
#define B_CBSQ 186646528ull             // 16KiB
#define B_ZERO 186712064ull             // 512B zero guard
// total ≈ 186.7 MB  (< 194.35 MB proven-safe in round 2)

// ---------- weight packing ----------
// encoder [oc][ic][4][4] f32 -> split-f16 B-fragment order:
// o = (((tap*8+icc)*16+n)*64+lane)*8+j ; ic=icc*32+(lane>>4)*8+j ; oc=n*16+(lane&15)
__global__ __launch_bounds__(256) void k_pack_enc(const float* __restrict__ w,
                                                  f16* __restrict__ Wh, f16* __restrict__ Wl){
  int o = blockIdx.x*256 + threadIdx.x;
  int j=o&7, l=(o>>3)&63, n=(o>>9)&15, icc=(o>>13)&7, tap=o>>16;
  int ic = icc*32 + (l>>4)*8 + j, oc = n*16 + (l&15);
  float v = w[((size_t)oc*256+ic)*16 + tap];
  f16 h = (f16)v;
  Wh[o]=h; Wl[o]=(f16)(v-(float)h);
}
// decoder [ic][oc][4][4] f32 -> bf16 packed, tap index = ky*4+kx
__global__ __launch_bounds__(256) void k_pack_dec(const float* __restrict__ w, u16* __restrict__ Wp){
  int o = blockIdx.x*256 + threadIdx.x;
  int j=o&7, l=(o>>3)&63, n=(o>>9)&15, icc=(o>>13)&7, tap=o>>16;
  int ic = icc*32 + (l>>4)*8 + j, oc = n*16 + (l&15);
  Wp[o] = f2bf(w[((size_t)ic*256+oc)*16 + tap]);
}
// codebook squared norms + zero the guard page
__global__ __launch_bounds__(256) void k_cbsq(const float* __restrict__ cb, float* __restrict__ cbsq,
                                              float* __restrict__ zg){
  int c = blockIdx.x*256 + threadIdx.x;
  if(blockIdx.x==0 && threadIdx.x<128) zg[threadIdx.x]=0.f;
  const float4* r4 = (const float4*)(cb + (size_t)c*256);
  float s = 0.f;
  for(int k=0;k<64;k++){ float4 v=r4[k]; s += v.x*v.x+v.y*v.y+v.z*v.z+v.w*v.w; }
  cbsq[c] = s;
}

// ---------- conv1: [B,1,64,64] f32 -> NHWC split-f16 [B,32,32,256] ----------
__global__ __launch_bounds__(256) void k_conv1(const float* __restrict__ x, const float* __restrict__ w1,
                                               const float* __restrict__ b1,
                                               f16* __restrict__ Oh, f16* __restrict__ Ol){
  int b = blockIdx.x >> 5, oy = blockIdx.x & 31;
  int oc = threadIdx.x;
  __shared__ float xs[4][68];            // input cols -1..64 => 66 used
  for(int i=threadIdx.x;i<264;i+=256){
    int rr=i/66, cc=i-rr*66;
    int iy=2*oy-1+rr, ix=cc-1;
    float v=0.f;
    if((unsigned)iy<64u && (unsigned)ix<64u) v = x[((size_t)b*64+iy)*64+ix];
    xs[rr][cc]=v;
  }
  __syncthreads();
  float wv[16];
  #pragma unroll
  for(int k=0;k<16;k++) wv[k]=w1[oc*16+k];
  float bv=b1[oc];
  for(int ox=0;ox<32;ox++){
    float acc=bv;
    int c0=2*ox;                         // input col (2*ox-1+kw)+1 = c0+kw in 0..65
    #pragma unroll
    for(int kh=0;kh<4;kh++)
      #pragma unroll
      for(int kw=0;kw<4;kw++) acc += wv[kh*4+kw]*xs[kh][c0+kw];
    float v = fmaxf(acc,0.f);
    f16 h=(f16)v;
    size_t o = (((size_t)b*32+oy)*32+ox)*256+oc;
    Oh[o]=h; Ol[o]=(f16)(v-(float)h);
  }
}

// ---------- encoder MFMA conv: stride-2 4x4, IC=OC=256, split-f16 ----------
template<int MT, bool RELU, bool F32OUT>
__global__ __launch_bounds__(256) void k_conv_mfma(
    const f16* __restrict__ Ah, const f16* __restrict__ Al,
    const f16* __restrict__ Wh, const f16* __restrict__ Wl,
    const float* __restrict__ bias,
    f16* __restrict__ Oh, f16* __restrict__ Ol, float* __restrict__ Of,
    const f16* __restrict__ Zp, int Hin){
  const int Hout = Hin>>1, HH = Hout*Hout;
  const int lane = threadIdx.x & 63, w = threadIdx.x >> 6;
  const int lr = lane & 15, lq = lane >> 4;
  const int m_base = blockIdx.x * (16*MT);
  int iyb[MT], ixb[MT], bb[MT];
  #pragma unroll
  for(int t=0;t<MT;t++){
    int m = m_base + t*16 + lr;
    int b = m/HH, rem = m - b*HH;
    int oy = rem/Hout, ox = rem - oy*Hout;
    bb[t]=b; iyb[t]=2*oy-1; ixb[t]=2*ox-1;
  }
  f32x4 zz = {0.f,0.f,0.f,0.f};
  f32x4 acc[MT][4];
  #pragma unroll
  for(int t=0;t<MT;t++)
    #pragma unroll
    for(int u=0;u<4;u++) acc[t][u]=zz;

  for(int tap=0;tap<16;tap++){
    int th=tap>>2, tw=tap&3;
    const f16* pH[MT]; const f16* pL[MT];
    #pragma unroll
    for(int t=0;t<MT;t++){
      int iy=iyb[t]+th, ix=ixb[t]+tw;
      bool val = ((unsigned)iy<(unsigned)Hin) && ((unsigned)ix<(unsigned)Hin);
      size_t o = (((size_t)bb[t]*Hin+iy)*Hin+ix)*256 + lq*8;
      pH[t] = val ? Ah+o : Zp;
      pL[t] = val ? Al+o : Zp;
    }
    #pragma unroll
    for(int icc=0;icc<8;icc++){
      f16x8 a_h[MT], a_l[MT];
      #pragma unroll
      for(int t=0;t<MT;t++){
        a_h[t] = *(const f16x8*)(pH[t] + icc*32);
        a_l[t] = *(const f16x8*)(pL[t] + icc*32);
      }
      size_t wb = ((size_t)(tap*8+icc)*16 + w*4)*512 + lane*8;
      #pragma unroll
      for(int u=0;u<4;u++){
        f16x8 b_h = *(const f16x8*)(Wh + wb + u*512);
        f16x8 b_l = *(const f16x8*)(Wl + wb + u*512);
        #pragma unroll
        for(int t=0;t<MT;t++){
          acc[t][u] = mfma_f16(a_h[t], b_h, acc[t][u]);
          acc[t][u] = mfma_f16(a_h[t], b_l, acc[t][u]);
          acc[t][u] = mfma_f16(a_l[t], b_h, acc[t][u]);
        }
      }
    }
  }
  #pragma unroll
  for(int t=0;t<MT;t++){
    #pragma unroll
    for(int u=0;u<4;u++){
      int n = (w*4+u)*16 + lr;
      float bv = bias[n];
      #pragma unroll
      for(int r=0;r<4;r++){
        int m = m_base + t*16 + lq*4 + r;
        float v = acc[t][u][r] + bv;
        if(RELU) v = fmaxf(v,0.f);
        size_t o = (size_t)m*256 + n;
        if(F32OUT){ Of[o]=v; }
        else { f16 h=(f16)v; Oh[o]=h; Ol[o]=(f16)(v-(float)h); }
      }
    }
  }
}

// ---------- decoder MFMA deconv (k4 s2 p1), parity-decomposed, bf16 ----------
template<int MT>
__global__ __launch_bounds__(256) void k_deconv_mfma(
    const u16* __restrict__ In, const u16* __restrict__ Wp,
    const float* __restrict__ bias, u16* __restrict__ Out,
    const u16* __restrict__ Zp, int H){
  const int Ho = H*2, HH = H*H;
  const int kh = blockIdx.y>>1, kw = blockIdx.y&1;
  const int lane = threadIdx.x & 63, w = threadIdx.x >> 6;
  const int lr = lane & 15, lq = lane >> 4;
  const int m_base = blockIdx.x * (16*MT);
  int jb[MT], ib[MT], bb[MT];
  #pragma unroll
  for(int t=0;t<MT;t++){
    int m = m_base + t*16 + lr;
    int b = m/HH, rem = m - b*HH;
    jb[t]=rem/H; ib[t]=rem-jb[t]*H; bb[t]=b;
  }
  f32x4 zz = {0.f,0.f,0.f,0.f};
  f32x4 acc[MT][4];
  #pragma unroll
  for(int t=0;t<MT;t++)
    #pragma unroll
    for(int u=0;u<4;u++) acc[t][u]=zz;

  #pragma unroll
  for(int dy=0;dy<2;dy++){
    #pragma unroll
    for(int dx=0;dx<2;dx++){
      int t16 = (kh+2*dy)*4 + (kw+2*dx);
      const u16* pA[MT];
      #pragma unroll
      for(int t=0;t<MT;t++){
        int r = jb[t]+(1-kh)-dy, c = ib[t]+(1-kw)-dx;
        bool val = ((unsigned)r<(unsigned)H) && ((unsigned)c<(unsigned)H);
        size_t o = (((size_t)bb[t]*H+r)*H+c)*256 + lq*8;
        pA[t] = val ? In+o : Zp;
      }
      #pragma unroll
      for(int icc=0;icc<8;icc++){
        s16x8 a[MT];
        #pragma unroll
        for(int t=0;t<MT;t++) a[t] = *(const s16x8*)(pA[t] + icc*32);
        size_t wb = ((size_t)(t16*8+icc)*16 + w*4)*512 + lane*8;
        #pragma unroll
        for(int u=0;u<4;u++){
          s16x8 bfr = *(const s16x8*)(Wp + wb + u*512);
          #pragma unroll
          for(int t=0;t<MT;t++) acc[t][u] = mfma_bf16(a[t], bfr, acc[t][u]);
        }
      }
    }
  }
  #pragma unroll
  for(int t=0;t<MT;t++){
    #pragma unroll
    for(int u=0;u<4;u++){
      int n = (w*4+u)*16 + lr;
      float bv = bias[n];
      #pragma unroll
      for(int r=0;r<4;r++){
        int m = m_base + t*16 + lq*4 + r;
        int b = m/HH, rem = m - b*HH;
        int j = rem/H, i = rem - j*H;
        int oy = 2*j + (1-kh), ox = 2*i + (1-kw);
        float v = fmaxf(acc[t][u][r] + bv, 0.f);
        Out[(((size_t)b*Ho+oy)*Ho+ox)*256 + n] = f2bf(v);
      }
    }
  }
}

// ---------- final deconv (OC=1) + sigmoid, NHWC bf16 input ----------
__global__ __launch_bounds__(256) void k_dec4(const u16* __restrict__ In, const float* __restrict__ w4,
                                              const float* __restrict__ bias, float* __restrict__ out){
  __shared__ float wt[16][256];
  int t = threadIdx.x;
  for(int i=t;i<4096;i+=256) wt[i&15][i>>4] = w4[i];
  __syncthreads();
  int ox = t & 63, oy = (blockIdx.x<<2) + (t>>6), b = blockIdx.y;
  int iyh=(oy+1)>>1, kh=(oy+1)&1;
  int ixh=(ox+1)>>1, kw=(ox+1)&1;
  float acc = bias[0];
  #pragma unroll
  for(int dy=0;dy<2;dy++){
    int r = iyh-dy;
    if((unsigned)r>=32u) continue;
    #pragma unroll
    for(int dx=0;dx<2;dx++){
      int c = ixh-dx;
      if((unsigned)c>=32u) continue;
      const u16* p = In + (((size_t)b*32+r)*32+c)*256;
      int widx = (kh+2*dy)*4 + kw+2*dx;
      float s=0.f;
      for(int ic=0;ic<256;ic+=8){
        s16x8 vv = *(const s16x8*)(p+ic);
        const float* wr = &wt[widx][ic];
        #pragma unroll
        for(int q=0;q<8;q++) s += bf2f((u16)vv[q])*wr[q];
      }
      acc += s;
    }
  }
  out[(size_t)b*4096 + oy*64 + ox] = 1.f/(1.f+__expf(-acc));
}

// ---------- zsq ----------
__global__ __launch_bounds__(256) void k_zsq(const float* __restrict__ zf, float* __restrict__ zsq){
  int r=blockIdx.x, c=threadIdx.x;
  float v = zf[(size_t)r*256+c];
  __shared__ float red[256];
  red[c]=v*v; __syncthreads();
  for(int s=128;s>0;s>>=1){ if(c<s) red[c]+=red[c+s]; __syncthreads(); }
  if(c==0) zsq[r]=red[0];
}

// ---------- f32 GEMM (VQ dots / dynamics head) ----------
template<int MODE>
__global__ __launch_bounds__(256) void k_gemm(const float* __restrict__ A, const float* __restrict__ Bm,
                                              const float* __restrict__ bias, float* __restrict__ C,
                                              int M, int N, int K){
  __shared__ __align__(16) float As[16][132];
  __shared__ __align__(16) float Bs[16][132];
  int m0 = blockIdx.y*128, n0 = blockIdx.x*128;
  int t = threadIdx.x;
  int tm = (t>>4)*8, tn = (t&15)*8;
  float acc[8][8] = {};
  for(int k0=0;k0<K;k0+=16){
    __syncthreads();
    for(int i=t;i<2048;i+=256){ int k=i&15, m=i>>4; As[k][m] = A[(size_t)(m0+m)*K + k0+k]; }
    if(MODE==0){
      for(int i=t;i<2048;i+=256){ int k=i&15, n=i>>4; Bs[k][n] = Bm[(size_t)(n0+n)*K + k0+k]; }
    } else {
      for(int i=t;i<2048;i+=256){ int n=i&127, k=i>>7; Bs[k][n] = Bm[(size_t)(k0+k)*N + n0+n]; }
    }
    __syncthreads();
    #pragma unroll
    for(int k=0;k<16;k++){
      float a[8], bb[8];
      *(float4*)&a[0]  = *(const float4*)&As[k][tm];
      *(float4*)&a[4]  = *(const float4*)&As[k][tm+4];
      *(float4*)&bb[0] = *(const float4*)&Bs[k][tn];
      *(float4*)&bb[4] = *(const float4*)&Bs[k][tn+4];
      #pragma unroll
      for(int i=0;i<8;i++)
        #pragma unroll
        for(int j=0;j<8;j++) acc[i][j] += a[i]*bb[j];
    }
  }
  if(MODE==0){
    #pragma unroll
    for(int i=0;i<8;i++)
      #pragma unroll
      for(int j=0;j<8;j+=4)
        *(float4*)&C[(size_t)(m0+tm+i)*N + n0+tn+j] = *(float4*)&acc[i][j];
  } else {
    float bv[8];
    #pragma unroll
    for(int j=0;j<8;j++) bv[j]=bias[n0+tn+j];
    #pragma unroll
    for(int i=0;i<8;i++)
      #pragma unroll
      for(int j=0;j<8;j++)
        C[(size_t)(m0+tm+i)*N + n0+tn+j] = acc[i][j]+bv[j];
  }
}

// ---------- VQ argmin (np.argmin first-min tie-break) ----------
__global__ __launch_bounds__(256) void k_argmin(const float* __restrict__ dots, const float* __restrict__ zsq,
                                                const float* __restrict__ cbsq, int* __restrict__ codes,
                                                float* __restrict__ out_codes){
  int r = blockIdx.x, t = threadIdx.x;
  float zs = zsq[r];
  float bv = 1e30f; int bi = 0x7fffffff;
  for(int c=t;c<4096;c+=256){
    float d = zs + cbsq[c] - 2.f*dots[(size_t)r*4096+c];
    if(d < bv || (d==bv && c<bi)){ bv=d; bi=c; }
  }
  __shared__ float sv[256]; __shared__ int si[256];
  sv[t]=bv; si[t]=bi; __syncthreads();
  for(int s=128;s>0;s>>=1){
    if(t<s){
      float v2=sv[t+s]; int i2=si[t+s];
      if(v2<sv[t] || (v2==sv[t] && i2<si[t])){ sv[t]=v2; si[t]=i2; }
    }
    __syncthreads();
  }
  if(t==0){ codes[r]=si[0]; out_codes[r]=(float)si[0]; }
}

__global__ void k_zero(float* a){ a[0]=0.f; }

// zq gather (bf16 NHWC for decoder) + loss accumulation
__global__ __launch_bounds__(256) void k_zqloss(const float* __restrict__ zf, const float* __restrict__ cb,
                                                const int* __restrict__ codes, u16* __restrict__ zq4,
                                                float* __restrict__ accum){
  int r = blockIdx.x, c = threadIdx.x;
  int code = codes[r];
  float q = cb[(size_t)code*256 + c];
  float d = zf[(size_t)r*256+c] - q;
  zq4[(size_t)r*256 + c] = f2bf(q);
  __shared__ float red[256];
  red[c]=d*d; __syncthreads();
  for(int s=128;s>0;s>>=1){ if(c<s) red[c]+=red[c+s]; __syncthreads(); }
  if(c==0) atomicAdd(accum, red[0]);
}

__global__ void k_final(const float* __restrict__ accum, float* __restrict__ out){
  if(threadIdx.x==0){
    float L = accum[0]*(1.f/524288.f);
    out[0]=L; out[1]=L; out[2]=1.25f*L;
  }
}

// ---------- dynamics ----------
__global__ __launch_bounds__(256) void k_embed(const int* __restrict__ codes, const int* __restrict__ action,
                                               const float* __restrict__ ce, const float* __restrict__ ae,
                                               float* __restrict__ emb){
  int b = blockIdx.x;
  for(int j=threadIdx.x;j<2176;j+=256){
    float v;
    if(j<2048){ int g=j>>7; v = ce[(size_t)codes[b*16+g]*128 + (j&127)]; }
    else      { v = ae[(size_t)action[b]*128 + (j-2048)]; }
    emb[(size_t)b*2176+j]=v;
  }
}

__global__ __launch_bounds__(256) void k_mlp(const float* __restrict__ in, const float* __restrict__ w,
                                             const float* __restrict__ bias, float* __restrict__ out, int K){
  int b = blockIdx.x, n = threadIdx.x;
  extern __shared__ float row[];
  for(int k=n;k<K;k+=256) row[k]=in[(size_t)b*K+k];
  __syncthreads();
  float acc = bias[n];
  for(int k=0;k<K;k++) acc += row[k]*w[(size_t)k*256+n];
  out[(size_t)b*256+n] = fmaxf(acc,0.f);
}

extern "C" void kernel_launch(void* const* d_in, const int* in_sizes, int n_in,
                              void* d_out, int out_size, void* d_ws, size_t ws_size,
                              hipStream_t stream){
  (void)in_sizes; (void)n_in; (void)out_size; (void)ws_size;
  const float* x    = (const float*)d_in[0];
  const float* xn   = (const float*)d_in[1];
  const int*   act  = (const int*)  d_in[2];
  const float* ew1=(const float*)d_in[3];  const float* eb1=(const float*)d_in[4];
  const float* ew2=(const float*)d_in[5];  const float* eb2=(const float*)d_in[6];
  const float* ew3=(const float*)d_in[7];  const float* eb3=(const float*)d_in[8];
  const float* ew4=(const float*)d_in[9];  const float* eb4=(const float*)d_in[10];
  const float* dw1=(const float*)d_in[11]; const float* db1=(const float*)d_in[12];
  const float* dw2=(const float*)d_in[13]; const float* db2=(const float*)d_in[14];
  const float* dw3=(const float*)d_in[15]; const float* db3=(const float*)d_in[16];
  const float* dw4=(const float*)d_in[17]; const float* db4=(const float*)d_in[18];
  const float* cbk =(const float*)d_in[19];
  const float* cemb=(const float*)d_in[20];
  const float* aemb=(const float*)d_in[21];
  const float* yw1=(const float*)d_in[22]; const float* yb1=(const float*)d_in[23];
  const float* yw2=(const float*)d_in[24]; const float* yb2=(const float*)d_in[25];
  const float* yw3=(const float*)d_in[26]; const float* yb3=(const float*)d_in[27];
  float* out = (float*)d_out;

  char* wsb = (char*)d_ws;
  f16* E1H=(f16*)(wsb+B_E1H); f16* E1L=(f16*)(wsb+B_E1L);
  f16* E2H=(f16*)(wsb+B_E2H); f16* E2L=(f16*)(wsb+B_E2L);
  f16* E3H=(f16*)(wsb+B_E3H); f16* E3L=(f16*)(wsb+B_E3L);
  float* ZF=(float*)(wsb+B_ZF);
  u16* ZQ4=(u16*)(wsb+B_ZQ4);
  f16* WE2H=(f16*)(wsb+B_WE2H); f16* WE2L=(f16*)(wsb+B_WE2L);
  f16* WE3H=(f16*)(wsb+B_WE3H); f16* WE3L=(f16*)(wsb+B_WE3L);
  f16* WE4H=(f16*)(wsb+B_WE4H); f16* WE4L=(f16*)(wsb+B_WE4L);
  u16* WD1=(u16*)(wsb+B_WD1); u16* WD2=(u16*)(wsb+B_WD2); u16* WD3=(u16*)(wsb+B_WD3);
  float* ZSQ=(float*)(wsb+B_ZSQ); float* CBSQ=(float*)(wsb+B_CBSQ);
  float* EMB=(float*)(wsb+B_EMB); float* H1=(float*)(wsb+B_H1); float* H2=(float*)(wsb+B_H2);
  float* ACC=(float*)(wsb+B_ACC); int* CODES=(int*)(wsb+B_CODES);
  float* ZG=(float*)(wsb+B_ZERO);
  const f16* Zf16=(const f16*)ZG; const u16* Zbf=(const u16*)ZG;
  float* DOTS=(float*)(wsb+B_DOTS);
  u16* D1=(u16*)(wsb+B_D1);
  u16* D2=(u16*)(wsb+B_D2);
  u16* D3=(u16*)(wsb+B_E1H);

  // weight prep
  k_pack_enc<<<4096,256,0,stream>>>(ew2, WE2H, WE2L);
  k_pack_enc<<<4096,256,0,stream>>>(ew3, WE3H, WE3L);
  k_pack_enc<<<4096,256,0,stream>>>(ew4, WE4H, WE4L);
  k_pack_dec<<<4096,256,0,stream>>>(dw1, WD1);
  k_pack_dec<<<4096,256,0,stream>>>(dw2, WD2);
  k_pack_dec<<<4096,256,0,stream>>>(dw3, WD3);
  k_cbsq<<<16,256,0,stream>>>(cbk, CBSQ, ZG);

  auto encode = [&](const float* img, float* code_out){
    k_conv1<<<4096,256,0,stream>>>(img, ew1, eb1, E1H, E1L);
    k_conv_mfma<4,true ,false><<<512,256,0,stream>>>(E1H,E1L, WE2H,WE2L, eb2, E2H,E2L, nullptr, Zf16, 32);
    k_conv_mfma<2,true ,false><<<256,256,0,stream>>>(E2H,E2L, WE3H,WE3L, eb3, E3H,E3L, nullptr, Zf16, 16);
    k_conv_mfma<1,false,true ><<<128,256,0,stream>>>(E3H,E3L, WE4H,WE4L, eb4, nullptr,nullptr, ZF, Zf16, 8);
    k_zsq<<<2048,256,0,stream>>>(ZF, ZSQ);
    k_gemm<0><<<dim3(32,16),256,0,stream>>>(ZF, cbk, nullptr, DOTS, 2048, 4096, 256);
    k_argmin<<<2048,256,0,stream>>>(DOTS, ZSQ, CBSQ, CODES, code_out);
  };

  // ---- encode(x) + VQ ----
  encode(x, out+OUT_CODES);
  k_zero<<<1,1,0,stream>>>(ACC);
  k_zqloss<<<2048,256,0,stream>>>(ZF, cbk, CODES, ZQ4, ACC);
  k_final<<<1,64,0,stream>>>(ACC, out+OUT_LC);

  // ---- decoder (bf16 MFMA) ----
  k_deconv_mfma<1><<<dim3(128,4),256,0,stream>>>(ZQ4, WD1, db1, D1, Zbf, 4);
  k_deconv_mfma<4><<<dim3(128,4),256,0,stream>>>(D1,  WD2, db2, D2, Zbf, 8);
  k_deconv_mfma<4><<<dim3(512,4),256,0,stream>>>(D2,  WD3, db3, D3, Zbf, 16);
  k_dec4<<<dim3(16,N_B),256,0,stream>>>(D3, dw4, db4, out+OUT_RECON);

  // ---- dynamics ----
  k_embed<<<N_B,256,0,stream>>>(CODES, act, cemb, aemb, EMB);
  k_mlp<<<N_B,256,2176*4,stream>>>(EMB, yw1, yb1, H1, 2176);
  k_mlp<<<N_B,256, 256*4,stream>>>(H1,  yw2, yb2, H2, 256);
  k_gemm<1><<<dim3(512,1),256,0,stream>>>(H2, yw3, yb3, out+OUT_NL, 128, 65536, 256);

  // ---- encode(x_next) ----
  encode(xn, out+OUT_NCT);
}

// Round 5
// 2026.278 us; speedup vs baseline: 5.0802x; 1.0520x over previous
//
#include <hip/hip_runtime.h>
#include <hip/hip_bf16.h>

typedef _Float16 f16;
typedef f16   f16x8 __attribute__((ext_vector_type(8)));
typedef short s16x8 __attribute__((ext_vector_type(8)));
typedef float f32x4 __attribute__((ext_vector_type(4)));
typedef unsigned short u16;

__device__ __forceinline__ f32x4 mfma_f16(f16x8 a, f16x8 b, f32x4 c){
  return __builtin_amdgcn_mfma_f32_16x16x32_f16(a,b,c,0,0,0);
}
__device__ __forceinline__ f32x4 mfma_bf16(s16x8 a, s16x8 b, f32x4 c){
  return __builtin_amdgcn_mfma_f32_16x16x32_bf16(a,b,c,0,0,0);
}
__device__ __forceinline__ u16 f2bf(float v){
  unsigned u = __float_as_uint(v);
  unsigned r = u + 0x7fffu + ((u>>16)&1u);
  return (u16)(r>>16);
}
__device__ __forceinline__ float bf2f(u16 v){ return __uint_as_float(((unsigned)v)<<16); }

#define N_B 128

// ---- output offsets (f32 elements), reference return order ----
#define OUT_RECON 0
#define OUT_CODES 524288
#define OUT_LC    526336
#define OUT_NL    526339
#define OUT_NCT   8914947

// ---- workspace layout (BYTE offsets) ----
// R1 (0..64MiB): E1H, later D3.  R2 (64..128MiB): E1L, later the small buffers
// below (lifetimes disjoint vs E1L which dies after conv2).  R3 (128..160MiB):
// E2H/E2L, later DOTS.  Persistent tail: packed weights, CBSQ, guard, CB pack.
#define B_E1H  0ull
#define B_E1L  67108864ull
#define B_ZF   67108864ull              // [2048,256] f32 (2MiB)
#define B_ZQ4  69206016ull              // [2048,256] bf16 (1MiB)
#define B_ZSQ  70254592ull
#define B_ACC  70287360ull
#define B_CODES 70320128ull
#define B_H1   70385664ull              // 128KiB
#define B_H2   70516736ull              // 128KiB
#define B_H2B  70647808ull              // [128,256] bf16 (64KiB)
#define B_E3H  71303168ull              // 4MiB (alias D1)
#define B_E3L  75497472ull              // 4MiB (alias D2 head)
#define B_D1   71303168ull
#define B_D2   75497472ull              // 16MiB
#define B_EMB  92274688ull              // ~1.1MiB
#define B_ZFH  100663296ull             // [2048,256] f16 (1MiB)
#define B_ZFL  101711872ull             // (1MiB)
#define B_E2H  134217728ull
#define B_E2L  150994944ull
#define B_DOTS 134217728ull             // 32MiB aliases E2
#define B_WE2H 167772160ull             // packed weights, 2MiB each
#define B_WE2L 169869312ull
#define B_WE3H 171966464ull
#define B_WE3L 174063616ull
#define B_WE4H 176160768ull
#define B_WE4L 178257920ull
#define B_WD1  180355072ull
#define B_WD2  182452224ull
#define B_WD3  184549376ull
#define B_CBSQ 186646528ull
#define B_ZERO 186712064ull             // 512B zero guard
#define B_CBH  186712576ull             // packed codebook h (2MiB)
#define B_CBL  188809728ull             // packed codebook l (2MiB) -> end 190906880
// total ≈ 190.9 MB  (< 194.35 MB proven-safe in round 2)

// ---------- weight packing ----------
// encoder [oc][ic][4][4] f32 -> split-f16 B-fragment order
__global__ __launch_bounds__(256) void k_pack_enc(const float* __restrict__ w,
                                                  f16* __restrict__ Wh, f16* __restrict__ Wl){
  int o = blockIdx.x*256 + threadIdx.x;
  int j=o&7, l=(o>>3)&63, n=(o>>9)&15, icc=(o>>13)&7, tap=o>>16;
  int ic = icc*32 + (l>>4)*8 + j, oc = n*16 + (l&15);
  float v = w[((size_t)oc*256+ic)*16 + tap];
  f16 h = (f16)v;
  Wh[o]=h; Wl[o]=(f16)(v-(float)h);
}
// decoder [ic][oc][4][4] f32 -> bf16 packed
__global__ __launch_bounds__(256) void k_pack_dec(const float* __restrict__ w, u16* __restrict__ Wp){
  int o = blockIdx.x*256 + threadIdx.x;
  int j=o&7, l=(o>>3)&63, n=(o>>9)&15, icc=(o>>13)&7, tap=o>>16;
  int ic = icc*32 + (l>>4)*8 + j, oc = n*16 + (l&15);
  Wp[o] = f2bf(w[((size_t)ic*256+oc)*16 + tap]);
}
// codebook [4096][256] f32 -> split-f16 B-fragment order (source-coalesced)
__global__ __launch_bounds__(256) void k_pack_cb(const float* __restrict__ cb,
                                                 f16* __restrict__ H, f16* __restrict__ L){
  int s = blockIdx.x*256 + threadIdx.x;      // s = n*256 + k
  int n = s>>8, k = s&255;
  float v = cb[s];
  int nt = n>>4, lr2 = n&15, icc = k>>5, rr = k&31, lq2 = rr>>3, j = rr&7;
  size_t o = ((size_t)(nt*8+icc)*64 + lq2*16 + lr2)*8 + j;
  f16 h = (f16)v; H[o]=h; L[o]=(f16)(v-(float)h);
}
// codebook squared norms + zero guard
__global__ __launch_bounds__(256) void k_cbsq(const float* __restrict__ cb, float* __restrict__ cbsq,
                                              float* __restrict__ zg){
  int c = blockIdx.x*256 + threadIdx.x;
  if(blockIdx.x==0 && threadIdx.x<128) zg[threadIdx.x]=0.f;
  const float4* r4 = (const float4*)(cb + (size_t)c*256);
  float s = 0.f;
  for(int k=0;k<64;k++){ float4 v=r4[k]; s += v.x*v.x+v.y*v.y+v.z*v.z+v.w*v.w; }
  cbsq[c] = s;
}

// ---------- conv1: [B,1,64,64] f32 -> NHWC split-f16 [B,32,32,256] ----------
__global__ __launch_bounds__(256) void k_conv1(const float* __restrict__ x, const float* __restrict__ w1,
                                               const float* __restrict__ b1,
                                               f16* __restrict__ Oh, f16* __restrict__ Ol){
  int b = blockIdx.x >> 5, oy = blockIdx.x & 31;
  int oc = threadIdx.x;
  __shared__ float xs[4][68];
  for(int i=threadIdx.x;i<264;i+=256){
    int rr=i/66, cc=i-rr*66;
    int iy=2*oy-1+rr, ix=cc-1;
    float v=0.f;
    if((unsigned)iy<64u && (unsigned)ix<64u) v = x[((size_t)b*64+iy)*64+ix];
    xs[rr][cc]=v;
  }
  __syncthreads();
  float wv[16];
  #pragma unroll
  for(int k=0;k<16;k++) wv[k]=w1[oc*16+k];
  float bv=b1[oc];
  for(int ox=0;ox<32;ox++){
    float acc=bv;
    int c0=2*ox;
    #pragma unroll
    for(int kh=0;kh<4;kh++)
      #pragma unroll
      for(int kw=0;kw<4;kw++) acc += wv[kh*4+kw]*xs[kh][c0+kw];
    float v = fmaxf(acc,0.f);
    f16 h=(f16)v;
    size_t o = (((size_t)b*32+oy)*32+ox)*256+oc;
    Oh[o]=h; Ol[o]=(f16)(v-(float)h);
  }
}

// ---------- encoder conv v2: LDS-staged A, stride-2 4x4, split-f16 ----------
// block 256 thr (4 waves). M-tile = 16*MT rows staged in LDS per tap; per tap
// two phases: H-phase (ah*bh + ah*bl), L-phase (al*bh) reusing one buffer.
template<int MT, int HIN>
__global__ __launch_bounds__(256,2) void k_conv_v2(
    const f16* __restrict__ Ah, const f16* __restrict__ Al,
    const f16* __restrict__ Wh, const f16* __restrict__ Wl,
    const float* __restrict__ bias, f16* __restrict__ Oh, f16* __restrict__ Ol){
  constexpr int HOUT = HIN/2, HH = HOUT*HOUT;
  constexpr int ROWS = MT*16, RS = 260;      // +4 halves pad: <=2-way LDS conflicts
  constexpr int REPS = MT*2;
  __shared__ f16 As[ROWS*RS];
  const int tid = threadIdx.x, lane = tid&63, w = tid>>6;
  const int lr = lane&15, lq = lane>>4;
  const int m_base = blockIdx.x*ROWS;
  // fixed staging assignment (per-thread) across taps
  int s_oy[REPS], s_ox[REPS], s_ls[REPS];
  size_t s_gb[REPS];
  #pragma unroll
  for(int rep=0;rep<REPS;rep++){
    int idx = rep*256 + tid;
    int ml = idx>>5, ch = idx&31;
    int m = m_base + ml;
    int b = m/HH, rem = m - b*HH;
    s_oy[rep] = rem/HOUT; s_ox[rep] = rem - s_oy[rep]*HOUT;
    s_gb[rep] = (size_t)b*HIN*HIN*256 + ch*8;
    s_ls[rep] = ml*RS + ch*8;
  }
  f32x4 acc[MT][4];
  #pragma unroll
  for(int t=0;t<MT;t++)
    #pragma unroll
    for(int u=0;u<4;u++) acc[t][u] = (f32x4){0.f,0.f,0.f,0.f};

  for(int tap=0;tap<16;tap++){
    const int th=tap>>2, tw=tap&3;
    // ---- phase H ----
    __syncthreads();
    #pragma unroll
    for(int rep=0;rep<REPS;rep++){
      int iy = 2*s_oy[rep]-1+th, ix = 2*s_ox[rep]-1+tw;
      f16x8 v = {0,0,0,0,0,0,0,0};
      if((unsigned)iy<(unsigned)HIN && (unsigned)ix<(unsigned)HIN)
        v = *(const f16x8*)(Ah + s_gb[rep] + (size_t)(iy*HIN+ix)*256);
      *(f16x8*)&As[s_ls[rep]] = v;
    }
    __syncthreads();
    #pragma unroll
    for(int icc=0;icc<8;icc++){
      f16x8 a[MT];
      #pragma unroll
      for(int t=0;t<MT;t++) a[t] = *(const f16x8*)&As[(t*16+lr)*RS + lq*8 + icc*32];
      size_t wb = ((size_t)(tap*8+icc)*16 + w*4)*512 + lane*8;
      #pragma unroll
      for(int u=0;u<4;u++){
        f16x8 b_h = *(const f16x8*)(Wh + wb + u*512);
        f16x8 b_l = *(const f16x8*)(Wl + wb + u*512);
        #pragma unroll
        for(int t=0;t<MT;t++){
          acc[t][u] = mfma_f16(a[t], b_h, acc[t][u]);
          acc[t][u] = mfma_f16(a[t], b_l, acc[t][u]);
        }
      }
    }
    // ---- phase L ----
    __syncthreads();
    #pragma unroll
    for(int rep=0;rep<REPS;rep++){
      int iy = 2*s_oy[rep]-1+th, ix = 2*s_ox[rep]-1+tw;
      f16x8 v = {0,0,0,0,0,0,0,0};
      if((unsigned)iy<(unsigned)HIN && (unsigned)ix<(unsigned)HIN)
        v = *(const f16x8*)(Al + s_gb[rep] + (size_t)(iy*HIN+ix)*256);
      *(f16x8*)&As[s_ls[rep]] = v;
    }
    __syncthreads();
    #pragma unroll
    for(int icc=0;icc<8;icc++){
      f16x8 a[MT];
      #pragma unroll
      for(int t=0;t<MT;t++) a[t] = *(const f16x8*)&As[(t*16+lr)*RS + lq*8 + icc*32];
      size_t wb = ((size_t)(tap*8+icc)*16 + w*4)*512 + lane*8;
      #pragma unroll
      for(int u=0;u<4;u++){
        f16x8 b_h = *(const f16x8*)(Wh + wb + u*512);
        #pragma unroll
        for(int t=0;t<MT;t++) acc[t][u] = mfma_f16(a[t], b_h, acc[t][u]);
      }
    }
  }
  #pragma unroll
  for(int t=0;t<MT;t++){
    #pragma unroll
    for(int u=0;u<4;u++){
      int n = (w*4+u)*16 + lr;
      float bv = bias[n];
      #pragma unroll
      for(int r=0;r<4;r++){
        int m = m_base + t*16 + lq*4 + r;
        float v = fmaxf(acc[t][u][r] + bv, 0.f);
        size_t o = (size_t)m*256 + n;
        f16 h=(f16)v; Oh[o]=h; Ol[o]=(f16)(v-(float)h);
      }
    }
  }
}

// ---------- legacy direct conv (conv4 only): f32 out + split-f16 zf ----------
template<int MT>
__global__ __launch_bounds__(256) void k_conv4(
    const f16* __restrict__ Ah, const f16* __restrict__ Al,
    const f16* __restrict__ Wh, const f16* __restrict__ Wl,
    const float* __restrict__ bias, float* __restrict__ Of,
    f16* __restrict__ Zh, f16* __restrict__ Zl,
    const f16* __restrict__ Zp, int Hin){
  const int Hout = Hin>>1, HH = Hout*Hout;
  const int lane = threadIdx.x & 63, w = threadIdx.x >> 6;
  const int lr = lane & 15, lq = lane >> 4;
  const int m_base = blockIdx.x * (16*MT);
  int iyb[MT], ixb[MT], bb[MT];
  #pragma unroll
  for(int t=0;t<MT;t++){
    int m = m_base + t*16 + lr;
    int b = m/HH, rem = m - b*HH;
    int oy = rem/Hout, ox = rem - oy*Hout;
    bb[t]=b; iyb[t]=2*oy-1; ixb[t]=2*ox-1;
  }
  f32x4 acc[MT][4];
  #pragma unroll
  for(int t=0;t<MT;t++)
    #pragma unroll
    for(int u=0;u<4;u++) acc[t][u]=(f32x4){0.f,0.f,0.f,0.f};

  for(int tap=0;tap<16;tap++){
    int th=tap>>2, tw=tap&3;
    const f16* pH[MT]; const f16* pL[MT];
    #pragma unroll
    for(int t=0;t<MT;t++){
      int iy=iyb[t]+th, ix=ixb[t]+tw;
      bool val = ((unsigned)iy<(unsigned)Hin) && ((unsigned)ix<(unsigned)Hin);
      size_t o = (((size_t)bb[t]*Hin+iy)*Hin+ix)*256 + lq*8;
      pH[t] = val ? Ah+o : Zp;
      pL[t] = val ? Al+o : Zp;
    }
    #pragma unroll
    for(int icc=0;icc<8;icc++){
      f16x8 a_h[MT], a_l[MT];
      #pragma unroll
      for(int t=0;t<MT;t++){
        a_h[t] = *(const f16x8*)(pH[t] + icc*32);
        a_l[t] = *(const f16x8*)(pL[t] + icc*32);
      }
      size_t wb = ((size_t)(tap*8+icc)*16 + w*4)*512 + lane*8;
      #pragma unroll
      for(int u=0;u<4;u++){
        f16x8 b_h = *(const f16x8*)(Wh + wb + u*512);
        f16x8 b_l = *(const f16x8*)(Wl + wb + u*512);
        #pragma unroll
        for(int t=0;t<MT;t++){
          acc[t][u] = mfma_f16(a_h[t], b_h, acc[t][u]);
          acc[t][u] = mfma_f16(a_h[t], b_l, acc[t][u]);
          acc[t][u] = mfma_f16(a_l[t], b_h, acc[t][u]);
        }
      }
    }
  }
  #pragma unroll
  for(int t=0;t<MT;t++){
    #pragma unroll
    for(int u=0;u<4;u++){
      int n = (w*4+u)*16 + lr;
      float bv = bias[n];
      #pragma unroll
      for(int r=0;r<4;r++){
        int m = m_base + t*16 + lq*4 + r;
        float v = acc[t][u][r] + bv;
        size_t o = (size_t)m*256 + n;
        Of[o]=v;
        f16 h=(f16)v; Zh[o]=h; Zl[o]=(f16)(v-(float)h);
      }
    }
  }
}

// ---------- decoder MFMA deconv (k4 s2 p1), parity-decomposed, bf16 ----------
template<int MT>
__global__ __launch_bounds__(256) void k_deconv_mfma(
    const u16* __restrict__ In, const u16* __restrict__ Wp,
    const float* __restrict__ bias, u16* __restrict__ Out,
    const u16* __restrict__ Zp, int H){
  const int Ho = H*2, HH = H*H;
  const int kh = blockIdx.y>>1, kw = blockIdx.y&1;
  const int lane = threadIdx.x & 63, w = threadIdx.x >> 6;
  const int lr = lane & 15, lq = lane >> 4;
  const int m_base = blockIdx.x * (16*MT);
  int jb[MT], ib[MT], bb[MT];
  #pragma unroll
  for(int t=0;t<MT;t++){
    int m = m_base + t*16 + lr;
    int b = m/HH, rem = m - b*HH;
    jb[t]=rem/H; ib[t]=rem-jb[t]*H; bb[t]=b;
  }
  f32x4 acc[MT][4];
  #pragma unroll
  for(int t=0;t<MT;t++)
    #pragma unroll
    for(int u=0;u<4;u++) acc[t][u]=(f32x4){0.f,0.f,0.f,0.f};

  #pragma unroll
  for(int dy=0;dy<2;dy++){
    #pragma unroll
    for(int dx=0;dx<2;dx++){
      int t16 = (kh+2*dy)*4 + (kw+2*dx);
      const u16* pA[MT];
      #pragma unroll
      for(int t=0;t<MT;t++){
        int r = jb[t]+(1-kh)-dy, c = ib[t]+(1-kw)-dx;
        bool val = ((unsigned)r<(unsigned)H) && ((unsigned)c<(unsigned)H);
        size_t o = (((size_t)bb[t]*H+r)*H+c)*256 + lq*8;
        pA[t] = val ? In+o : Zp;
      }
      #pragma unroll
      for(int icc=0;icc<8;icc++){
        s16x8 a[MT];
        #pragma unroll
        for(int t=0;t<MT;t++) a[t] = *(const s16x8*)(pA[t] + icc*32);
        size_t wb = ((size_t)(t16*8+icc)*16 + w*4)*512 + lane*8;
        #pragma unroll
        for(int u=0;u<4;u++){
          s16x8 bfr = *(const s16x8*)(Wp + wb + u*512);
          #pragma unroll
          for(int t=0;t<MT;t++) acc[t][u] = mfma_bf16(a[t], bfr, acc[t][u]);
        }
      }
    }
  }
  #pragma unroll
  for(int t=0;t<MT;t++){
    #pragma unroll
    for(int u=0;u<4;u++){
      int n = (w*4+u)*16 + lr;
      float bv = bias[n];
      #pragma unroll
      for(int r=0;r<4;r++){
        int m = m_base + t*16 + lq*4 + r;
        int b = m/HH, rem = m - b*HH;
        int j = rem/H, i = rem - j*H;
        int oy = 2*j + (1-kh), ox = 2*i + (1-kw);
        float v = fmaxf(acc[t][u][r] + bv, 0.f);
        Out[(((size_t)b*Ho+oy)*Ho+ox)*256 + n] = f2bf(v);
      }
    }
  }
}

// ---------- final deconv (OC=1) + sigmoid ----------
__global__ __launch_bounds__(256) void k_dec4(const u16* __restrict__ In, const float* __restrict__ w4,
                                              const float* __restrict__ bias, float* __restrict__ out){
  __shared__ float wt[16][256];
  int t = threadIdx.x;
  for(int i=t;i<4096;i+=256) wt[i&15][i>>4] = w4[i];
  __syncthreads();
  int ox = t & 63, oy = (blockIdx.x<<2) + (t>>6), b = blockIdx.y;
  int iyh=(oy+1)>>1, kh=(oy+1)&1;
  int ixh=(ox+1)>>1, kw=(ox+1)&1;
  float acc = bias[0];
  #pragma unroll
  for(int dy=0;dy<2;dy++){
    int r = iyh-dy;
    if((unsigned)r>=32u) continue;
    #pragma unroll
    for(int dx=0;dx<2;dx++){
      int c = ixh-dx;
      if((unsigned)c>=32u) continue;
      const u16* p = In + (((size_t)b*32+r)*32+c)*256;
      int widx = (kh+2*dy)*4 + kw+2*dx;
      float s=0.f;
      for(int ic=0;ic<256;ic+=8){
        s16x8 vv = *(const s16x8*)(p+ic);
        const float* wr = &wt[widx][ic];
        #pragma unroll
        for(int q=0;q<8;q++) s += bf2f((u16)vv[q])*wr[q];
      }
      acc += s;
    }
  }
  out[(size_t)b*4096 + oy*64 + ox] = 1.f/(1.f+__expf(-acc));
}

// ---------- zsq ----------
__global__ __launch_bounds__(256) void k_zsq(const float* __restrict__ zf, float* __restrict__ zsq){
  int r=blockIdx.x, c=threadIdx.x;
  float v = zf[(size_t)r*256+c];
  __shared__ float red[256];
  red[c]=v*v; __syncthreads();
  for(int s=128;s>0;s>>=1){ if(c<s) red[c]+=red[c+s]; __syncthreads(); }
  if(c==0) zsq[r]=red[0];
}

// ---------- VQ dots via split-f16 MFMA: D[2048][4096] = ZF * CB^T ----------
__global__ __launch_bounds__(256,2) void k_dots(
    const f16* __restrict__ ZH, const f16* __restrict__ ZL,
    const f16* __restrict__ CH, const f16* __restrict__ CL, float* __restrict__ D){
  const int lane = threadIdx.x & 63, w = threadIdx.x >> 6;
  const int lr = lane & 15, lq = lane >> 4;
  const int m_base = blockIdx.y*64, nb = blockIdx.x;
  f32x4 acc[4][4];
  #pragma unroll
  for(int t=0;t<4;t++)
    #pragma unroll
    for(int u=0;u<4;u++) acc[t][u]=(f32x4){0.f,0.f,0.f,0.f};
  #pragma unroll
  for(int icc=0;icc<8;icc++){
    f16x8 ah[4], al[4];
    #pragma unroll
    for(int t=0;t<4;t++){
      size_t o = (size_t)(m_base + t*16 + lr)*256 + lq*8 + icc*32;
      ah[t] = *(const f16x8*)(ZH+o);
      al[t] = *(const f16x8*)(ZL+o);
    }
    #pragma unroll
    for(int u=0;u<4;u++){
      int nt = nb*16 + w*4 + u;
      size_t wb = ((size_t)(nt*8+icc)*64 + lane)*8;
      f16x8 b_h = *(const f16x8*)(CH+wb);
      f16x8 b_l = *(const f16x8*)(CL+wb);
      #pragma unroll
      for(int t=0;t<4;t++){
        acc[t][u] = mfma_f16(ah[t], b_h, acc[t][u]);
        acc[t][u] = mfma_f16(ah[t], b_l, acc[t][u]);
        acc[t][u] = mfma_f16(al[t], b_h, acc[t][u]);
      }
    }
  }
  #pragma unroll
  for(int t=0;t<4;t++)
    #pragma unroll
    for(int u=0;u<4;u++){
      int n = nb*256 + (w*4+u)*16 + lr;
      #pragma unroll
      for(int r=0;r<4;r++){
        int m = m_base + t*16 + lq*4 + r;
        D[(size_t)m*4096 + n] = acc[t][u][r];
      }
    }
}

// ---------- VQ argmin ----------
__global__ __launch_bounds__(256) void k_argmin(const float* __restrict__ dots, const float* __restrict__ zsq,
                                                const float* __restrict__ cbsq, int* __restrict__ codes,
                                                float* __restrict__ out_codes){
  int r = blockIdx.x, t = threadIdx.x;
  float zs = zsq[r];
  float bv = 1e30f; int bi = 0x7fffffff;
  for(int c=t;c<4096;c+=256){
    float d = zs + cbsq[c] - 2.f*dots[(size_t)r*4096+c];
    if(d < bv || (d==bv && c<bi)){ bv=d; bi=c; }
  }
  __shared__ float sv[256]; __shared__ int si[256];
  sv[t]=bv; si[t]=bi; __syncthreads();
  for(int s=128;s>0;s>>=1){
    if(t<s){
      float v2=sv[t+s]; int i2=si[t+s];
      if(v2<sv[t] || (v2==sv[t] && i2<si[t])){ sv[t]=v2; si[t]=i2; }
    }
    __syncthreads();
  }
  if(t==0){ codes[r]=si[0]; out_codes[r]=(float)si[0]; }
}

__global__ void k_zero(float* a){ a[0]=0.f; }

// zq gather (bf16 NHWC) + loss accumulation
__global__ __launch_bounds__(256) void k_zqloss(const float* __restrict__ zf, const float* __restrict__ cb,
                                                const int* __restrict__ codes, u16* __restrict__ zq4,
                                                float* __restrict__ accum){
  int r = blockIdx.x, c = threadIdx.x;
  int code = codes[r];
  float q = cb[(size_t)code*256 + c];
  float d = zf[(size_t)r*256+c] - q;
  zq4[(size_t)r*256 + c] = f2bf(q);
  __shared__ float red[256];
  red[c]=d*d; __syncthreads();
  for(int s=128;s>0;s>>=1){ if(c<s) red[c]+=red[c+s]; __syncthreads(); }
  if(c==0) atomicAdd(accum, red[0]);
}

__global__ void k_final(const float* __restrict__ accum, float* __restrict__ out){
  if(threadIdx.x==0){
    float L = accum[0]*(1.f/524288.f);
    out[0]=L; out[1]=L; out[2]=1.25f*L;
  }
}

// ---------- dynamics ----------
__global__ __launch_bounds__(256) void k_embed(const int* __restrict__ codes, const int* __restrict__ action,
                                               const float* __restrict__ ce, const float* __restrict__ ae,
                                               float* __restrict__ emb){
  int b = blockIdx.x;
  for(int j=threadIdx.x;j<2176;j+=256){
    float v;
    if(j<2048){ int g=j>>7; v = ce[(size_t)codes[b*16+g]*128 + (j&127)]; }
    else      { v = ae[(size_t)action[b]*128 + (j-2048)]; }
    emb[(size_t)b*2176+j]=v;
  }
}

__global__ __launch_bounds__(256) void k_mlp(const float* __restrict__ in, const float* __restrict__ w,
                                             const float* __restrict__ bias, float* __restrict__ out,
                                             u16* __restrict__ outb, int K){
  int b = blockIdx.x, n = threadIdx.x;
  extern __shared__ float row[];
  for(int k=n;k<K;k+=256) row[k]=in[(size_t)b*K+k];
  __syncthreads();
  float acc = bias[n];
  for(int k=0;k<K;k++) acc += row[k]*w[(size_t)k*256+n];
  float v = fmaxf(acc,0.f);
  out[(size_t)b*256+n] = v;
  if(outb) outb[(size_t)b*256+n] = f2bf(v);
}

// ---------- dynamics head: [128,65536] = H2[128,256] @ W3 + b3, bf16 MFMA ----------
__global__ __launch_bounds__(256,2) void k_head(const u16* __restrict__ A,
                                                const float* __restrict__ w3,
                                                const float* __restrict__ b3,
                                                float* __restrict__ O){
  __shared__ u16 BS[8*64*8];                 // 8 n-tiles x 64 lanes x 8 = 8KB
  const int tid = threadIdx.x, lane = tid&63, w = tid>>6;
  const int lr = lane&15, lq = lane>>4;
  const int nb = blockIdx.x;                 // 512 blocks of n=128
  f32x4 acc[8][2];
  #pragma unroll
  for(int mt=0;mt<8;mt++)
    #pragma unroll
    for(int u=0;u<2;u++) acc[mt][u]=(f32x4){0.f,0.f,0.f,0.f};
  for(int icc=0;icc<8;icc++){
    __syncthreads();
    #pragma unroll
    for(int q=0;q<4;q++){
      int s = tid*16 + q*4;                  // [k=32][n=128] chunk, coalesced
      int kl = s>>7, nl = s&127;
      float4 v = *(const float4*)(w3 + (size_t)(icc*32+kl)*65536 + (size_t)nb*128 + nl);
      float vv[4] = {v.x,v.y,v.z,v.w};
      int j = kl&7, lqk = kl>>3;
      #pragma unroll
      for(int e=0;e<4;e++){
        int n2 = nl+e, ntl = n2>>4, lr2 = n2&15;
        BS[(ntl*64 + lqk*16 + lr2)*8 + j] = f2bf(vv[e]);
      }
    }
    __syncthreads();
    s16x8 a[8];
    #pragma unroll
    for(int mt=0;mt<8;mt++)
      a[mt] = *(const s16x8*)(A + (size_t)(mt*16+lr)*256 + icc*32 + lq*8);
    #pragma unroll
    for(int u=0;u<2;u++){
      int ntl = w*2+u;
      s16x8 bfr = *(const s16x8*)&BS[((size_t)ntl*64 + lane)*8];
      #pragma unroll
      for(int mt=0;mt<8;mt++) acc[mt][u] = mfma_bf16(a[mt], bfr, acc[mt][u]);
    }
  }
  #pragma unroll
  for(int mt=0;mt<8;mt++)
    #pragma unroll
    for(int u=0;u<2;u++){
      int n = nb*128 + (w*2+u)*16 + lr;
      float bv = b3[n];
      #pragma unroll
      for(int r=0;r<4;r++){
        int m = mt*16 + lq*4 + r;
        O[(size_t)m*65536 + n] = acc[mt][u][r] + bv;
      }
    }
}

extern "C" void kernel_launch(void* const* d_in, const int* in_sizes, int n_in,
                              void* d_out, int out_size, void* d_ws, size_t ws_size,
                              hipStream_t stream){
  (void)in_sizes; (void)n_in; (void)out_size; (void)ws_size;
  const float* x    = (const float*)d_in[0];
  const float* xn   = (const float*)d_in[1];
  const int*   act  = (const int*)  d_in[2];
  const float* ew1=(const float*)d_in[3];  const float* eb1=(const float*)d_in[4];
  const float* ew2=(const float*)d_in[5];  const float* eb2=(const float*)d_in[6];
  const float* ew3=(const float*)d_in[7];  const float* eb3=(const float*)d_in[8];
  const float* ew4=(const float*)d_in[9];  const float* eb4=(const float*)d_in[10];
  const float* dw1=(const float*)d_in[11]; const float* db1=(const float*)d_in[12];
  const float* dw2=(const float*)d_in[13]; const float* db2=(const float*)d_in[14];
  const float* dw3=(const float*)d_in[15]; const float* db3=(const float*)d_in[16];
  const float* dw4=(const float*)d_in[17]; const float* db4=(const float*)d_in[18];
  const float* cbk =(const float*)d_in[19];
  const float* cemb=(const float*)d_in[20];
  const float* aemb=(const float*)d_in[21];
  const float* yw1=(const float*)d_in[22]; const float* yb1=(const float*)d_in[23];
  const float* yw2=(const float*)d_in[24]; const float* yb2=(const float*)d_in[25];
  const float* yw3=(const float*)d_in[26]; const float* yb3=(const float*)d_in[27];
  float* out = (float*)d_out;

  char* wsb = (char*)d_ws;
  f16* E1H=(f16*)(wsb+B_E1H); f16* E1L=(f16*)(wsb+B_E1L);
  f16* E2H=(f16*)(wsb+B_E2H); f16* E2L=(f16*)(wsb+B_E2L);
  f16* E3H=(f16*)(wsb+B_E3H); f16* E3L=(f16*)(wsb+B_E3L);
  float* ZF=(float*)(wsb+B_ZF);
  f16* ZFH=(f16*)(wsb+B_ZFH); f16* ZFL=(f16*)(wsb+B_ZFL);
  u16* ZQ4=(u16*)(wsb+B_ZQ4);
  f16* WE2H=(f16*)(wsb+B_WE2H); f16* WE2L=(f16*)(wsb+B_WE2L);
  f16* WE3H=(f16*)(wsb+B_WE3H); f16* WE3L=(f16*)(wsb+B_WE3L);
  f16* WE4H=(f16*)(wsb+B_WE4H); f16* WE4L=(f16*)(wsb+B_WE4L);
  u16* WD1=(u16*)(wsb+B_WD1); u16* WD2=(u16*)(wsb+B_WD2); u16* WD3=(u16*)(wsb+B_WD3);
  f16* CBH=(f16*)(wsb+B_CBH); f16* CBL=(f16*)(wsb+B_CBL);
  float* ZSQ=(float*)(wsb+B_ZSQ); float* CBSQ=(float*)(wsb+B_CBSQ);
  float* EMB=(float*)(wsb+B_EMB); float* H1=(float*)(wsb+B_H1); float* H2=(float*)(wsb+B_H2);
  u16* H2B=(u16*)(wsb+B_H2B);
  float* ACC=(float*)(wsb+B_ACC); int* CODES=(int*)(wsb+B_CODES);
  float* ZG=(float*)(wsb+B_ZERO);
  const f16* Zf16=(const f16*)ZG; const u16* Zbf=(const u16*)ZG;
  float* DOTS=(float*)(wsb+B_DOTS);
  u16* D1=(u16*)(wsb+B_D1);
  u16* D2=(u16*)(wsb+B_D2);
  u16* D3=(u16*)(wsb+B_E1H);

  // weight prep
  k_pack_enc<<<4096,256,0,stream>>>(ew2, WE2H, WE2L);
  k_pack_enc<<<4096,256,0,stream>>>(ew3, WE3H, WE3L);
  k_pack_enc<<<4096,256,0,stream>>>(ew4, WE4H, WE4L);
  k_pack_dec<<<4096,256,0,stream>>>(dw1, WD1);
  k_pack_dec<<<4096,256,0,stream>>>(dw2, WD2);
  k_pack_dec<<<4096,256,0,stream>>>(dw3, WD3);
  k_pack_cb <<<4096,256,0,stream>>>(cbk, CBH, CBL);
  k_cbsq<<<16,256,0,stream>>>(cbk, CBSQ, ZG);

  auto encode = [&](const float* img, float* code_out){
    k_conv1<<<4096,256,0,stream>>>(img, ew1, eb1, E1H, E1L);
    k_conv_v2<4,32><<<512,256,0,stream>>>(E1H,E1L, WE2H,WE2L, eb2, E2H,E2L);
    k_conv_v2<2,16><<<256,256,0,stream>>>(E2H,E2L, WE3H,WE3L, eb3, E3H,E3L);
    k_conv4<1><<<128,256,0,stream>>>(E3H,E3L, WE4H,WE4L, eb4, ZF, ZFH, ZFL, Zf16, 8);
    k_zsq<<<2048,256,0,stream>>>(ZF, ZSQ);
    k_dots<<<dim3(16,32),256,0,stream>>>(ZFH, ZFL, CBH, CBL, DOTS);
    k_argmin<<<2048,256,0,stream>>>(DOTS, ZSQ, CBSQ, CODES, code_out);
  };

  // ---- encode(x) + VQ ----
  encode(x, out+OUT_CODES);
  k_zero<<<1,1,0,stream>>>(ACC);
  k_zqloss<<<2048,256,0,stream>>>(ZF, cbk, CODES, ZQ4, ACC);
  k_final<<<1,64,0,stream>>>(ACC, out+OUT_LC);

  // ---- decoder (bf16 MFMA) ----
  k_deconv_mfma<1><<<dim3(128,4),256,0,stream>>>(ZQ4, WD1, db1, D1, Zbf, 4);
  k_deconv_mfma<4><<<dim3(128,4),256,0,stream>>>(D1,  WD2, db2, D2, Zbf, 8);
  k_deconv_mfma<4><<<dim3(512,4),256,0,stream>>>(D2,  WD3, db3, D3, Zbf, 16);
  k_dec4<<<dim3(16,N_B),256,0,stream>>>(D3, dw4, db4, out+OUT_RECON);

  // ---- dynamics ----
  k_embed<<<N_B,256,0,stream>>>(CODES, act, cemb, aemb, EMB);
  k_mlp<<<N_B,256,2176*4,stream>>>(EMB, yw1, yb1, H1, nullptr, 2176);
  k_mlp<<<N_B,256, 256*4,stream>>>(H1,  yw2, yb2, H2, H2B, 256);
  k_head<<<512,256,0,stream>>>(H2B, yw3, yb3, out+OUT_NL);

  // ---- encode(x_next) ----
  encode(xn, out+OUT_NCT);
}